// Round 12
// baseline (407.392 us; speedup 1.0000x reference)
//
#include <hip/hip_runtime.h>
#include <hip/hip_bf16.h>
#include <cstdint>

// Problem constants (fixed by the reference harness)
#define NN 32768      // nodes per graph
#define EE 262144     // edges per graph
#define MM 65536      // 2*NN combined rows
#define HH 512
#define BB 64
#define DIN 20
#define BN_EPS 1e-5f

// ---------- bf16 helpers (bit-level, fast) ----------
__device__ __forceinline__ float bflo(uint32_t w) { return __builtin_bit_cast(float, w << 16); }
__device__ __forceinline__ float bfhi(uint32_t w) { return __builtin_bit_cast(float, w & 0xffff0000u); }
__device__ __forceinline__ uint32_t f2bf_u(float f) {
  uint32_t u = __builtin_bit_cast(uint32_t, f);
  return (u + 0x7fffu + ((u >> 16) & 1u)) >> 16;   // RTNE
}
__device__ __forceinline__ uint32_t pack2(float lo, float hi) {
  return f2bf_u(lo) | (f2bf_u(hi) << 16);
}

typedef float f32x4 __attribute__((ext_vector_type(4)));
typedef float f32x2 __attribute__((ext_vector_type(2)));
typedef long longx2 __attribute__((ext_vector_type(2)));

__device__ __forceinline__ void gl2lds16(const void* g, void* l) {
  __builtin_amdgcn_global_load_lds(
      (const __attribute__((address_space(1))) void*)g,
      (__attribute__((address_space(3))) void*)l, 16, 0, 0);
}

// ---------- prep+deg merged: deg histogram AND W2 -> fp8 transposed AND Wf fold ----------
__global__ void prep_deg_kernel(const int* __restrict__ dst1, const int* __restrict__ dst2,
                                int* __restrict__ deg_cnt,
                                const float* __restrict__ W2, uint32_t* __restrict__ Wt8,
                                const float* __restrict__ Wi, const float* __restrict__ bi,
                                const float* __restrict__ W1, float* __restrict__ Wf) {
  int bid = blockIdx.x;
  if (bid < 2048) {
    int e = bid * 256 + threadIdx.x;            // < 2*EE
    int g = e >> 18, le = e & 0x3ffff;
    int d = (g ? dst2 : dst1)[le];
    atomicAdd(&deg_cnt[g * NN + d], 1);
  } else if (bid < 2304) {
    // W2 [k][n] fp32 -> Wt8 [n][k] fp8-e4m3 (fp8 GEMM B-operand)
    int idx = (bid - 2048) * 256 + threadIdx.x; // < 512*128
    int n = idx >> 7, k4 = idx & 127;
    int k = k4 * 4;
    float w0 = W2[(size_t)k * HH + n];
    float w1 = W2[(size_t)(k + 1) * HH + n];
    float w2v = W2[(size_t)(k + 2) * HH + n];
    float w3 = W2[(size_t)(k + 3) * HH + n];
    uint32_t p = __builtin_amdgcn_cvt_pk_fp8_f32(w0, w1, 0u, false);
    p = __builtin_amdgcn_cvt_pk_fp8_f32(w2v, w3, p, true);
    Wt8[(size_t)n * 128 + k4] = p;
  } else {
    int idx = (bid - 2304) * 256 + threadIdx.x; // < 21*512
    if (idx >= 21 * 512) return;
    int k = idx >> 9, n = idx & 511;
    float s = 0.f;
    if (k < 20) {
      const float* wr = Wi + (size_t)k * HH;
      for (int j = 0; j < HH; j++) s = fmaf(wr[j], W1[(size_t)j * HH + n], s);
    } else {
      for (int j = 0; j < HH; j++) s = fmaf(bi[j], W1[(size_t)j * HH + n], s);
    }
    Wf[idx] = s;
  }
}

// ---------- CSR build ----------
__global__ void scan_kernel(const int* __restrict__ deg_cnt, int* __restrict__ offsets,
                            int* __restrict__ cursor) {
  int g = blockIdx.x;
  const int* d = deg_cnt + g * NN;
  int* off = offsets + g * (NN + 1);
  int* cur = cursor + g * NN;
  int t = threadIdx.x;                          // 1024 threads
  int base = t * 32;
  int loc[32]; int s = 0;
#pragma unroll
  for (int i = 0; i < 32; i++) { loc[i] = d[base + i]; s += loc[i]; }
  __shared__ int sm[1024];
  sm[t] = s; __syncthreads();
  for (int ofs = 1; ofs < 1024; ofs <<= 1) {
    int v = sm[t];
    int add = (t >= ofs) ? sm[t - ofs] : 0;
    __syncthreads();
    sm[t] = v + add;
    __syncthreads();
  }
  int run = (t == 0) ? 0 : sm[t - 1];
#pragma unroll
  for (int i = 0; i < 32; i++) { off[base + i] = run; cur[base + i] = run; run += loc[i]; }
  if (t == 1023) off[NN] = run;
}

__global__ void scatter_kernel(const int* __restrict__ src1, const int* __restrict__ dst1,
                               const int* __restrict__ src2, const int* __restrict__ dst2,
                               int* __restrict__ cursor, int* __restrict__ csr) {
  int e = blockIdx.x * 256 + threadIdx.x;       // < 2*EE
  int g = e >> 18, le = e & 0x3ffff;
  int d = (g ? dst2 : dst1)[le];
  int s = (g ? src2 : src1)[le];
  int pos = atomicAdd(&cursor[g * NN + d], 1);
  csr[g * EE + pos] = s;
}

// ---------- z1 (xagg fused): z1 = xa@Wf + bf*bvec + b1, fp8 output ONLY ----------
// Edge-parallel gather (4 lanes/row), 512-thread blocks (R9 best-measured).
__global__ __launch_bounds__(512) void z1_kernel(const float* __restrict__ x1,
                          const float* __restrict__ x2,
                          const int* __restrict__ csr, const int* __restrict__ offsets,
                          const float* __restrict__ Wf, const float* __restrict__ b1,
                          uint32_t* __restrict__ z8, float* __restrict__ pstat) {
  __shared__ float xas[128][21];    // 21-pad: conflict-free writes
  __shared__ float sred[512][8];
  int t = threadIdx.x;
  int r0 = blockIdx.x * 128;        // 512 blocks x 128 rows; never straddles graphs
  int g = r0 >> 15;
  const float* xg = g ? x2 : x1;
  const int* off = offsets + g * (NN + 1);
  const int* cs = csr + g * EE;

  // ---- phase 1: xa = x + mean_nbr x (4 lanes/row, edge-parallel) ----
  {
    int row = t >> 2;               // 128 rows
    int q = t & 3;
    int n = (r0 + row) & (NN - 1);
    int e0 = off[n], e1 = off[n + 1];
    float4 a4[5] = {};
    for (int e = e0 + q; e < e1; e += 4) {
      const float4* xr = (const float4*)(xg + (size_t)cs[e] * DIN);
#pragma unroll
      for (int k = 0; k < 5; k++) {
        float4 v = xr[k];
        a4[k].x += v.x; a4[k].y += v.y; a4[k].z += v.z; a4[k].w += v.w;
      }
    }
    // butterfly across the 4 lanes of this row (all lanes end with full sums)
#pragma unroll
    for (int k = 0; k < 5; k++) {
      a4[k].x += __shfl_xor(a4[k].x, 1); a4[k].y += __shfl_xor(a4[k].y, 1);
      a4[k].z += __shfl_xor(a4[k].z, 1); a4[k].w += __shfl_xor(a4[k].w, 1);
      a4[k].x += __shfl_xor(a4[k].x, 2); a4[k].y += __shfl_xor(a4[k].y, 2);
      a4[k].z += __shfl_xor(a4[k].z, 2); a4[k].w += __shfl_xor(a4[k].w, 2);
    }
    if (q == 0) {
      float inv = (e1 > e0) ? 1.f / (float)(e1 - e0) : 0.f;
      const float4* xs = (const float4*)(xg + (size_t)n * DIN);
#pragma unroll
      for (int k = 0; k < 5; k++) {
        float4 v = xs[k];
        xas[row][k * 4 + 0] = fmaf(a4[k].x, inv, v.x);
        xas[row][k * 4 + 1] = fmaf(a4[k].y, inv, v.y);
        xas[row][k * 4 + 2] = fmaf(a4[k].z, inv, v.z);
        xas[row][k * 4 + 3] = fmaf(a4[k].w, inv, v.w);
      }
    }
  }
  __syncthreads();

  // ---- phase 2: GEMV over 512 cols (128 col-threads x 4 row-groups) ----
  int col0 = (t & 127) * 4;
  int rq = t >> 7;                  // wave-uniform

  float w[DIN][4];
#pragma unroll
  for (int k = 0; k < DIN; k++) {
    float4 wv = *(const float4*)(Wf + (size_t)k * HH + col0);
    w[k][0] = wv.x; w[k][1] = wv.y; w[k][2] = wv.z; w[k][3] = wv.w;
  }
  float4 bvv = *(const float4*)(Wf + (size_t)DIN * HH + col0);   // bi @ W1
  float4 b1v = *(const float4*)(b1 + col0);

  float s4[4] = {0.f, 0.f, 0.f, 0.f}, q4[4] = {0.f, 0.f, 0.f, 0.f};
  for (int rr = 0; rr < 32; rr++) {
    int row = rr * 4 + rq;
    int grow = r0 + row;
    int n = grow & (NN - 1);
    float bf = (off[n + 1] - off[n] > 0) ? 2.f : 1.f;   // wave-uniform
    float a0 = fmaf(bvv.x, bf, b1v.x), a1 = fmaf(bvv.y, bf, b1v.y);
    float a2 = fmaf(bvv.z, bf, b1v.z), a3 = fmaf(bvv.w, bf, b1v.w);
#pragma unroll
    for (int k = 0; k < DIN; k++) {
      float xv = xas[row][k];       // uniform addr within wave -> LDS broadcast
      a0 = fmaf(xv, w[k][0], a0);
      a1 = fmaf(xv, w[k][1], a1);
      a2 = fmaf(xv, w[k][2], a2);
      a3 = fmaf(xv, w[k][3], a3);
    }
    s4[0] += a0; q4[0] = fmaf(a0, a0, q4[0]);
    s4[1] += a1; q4[1] = fmaf(a1, a1, q4[1]);
    s4[2] += a2; q4[2] = fmaf(a2, a2, q4[2]);
    s4[3] += a3; q4[3] = fmaf(a3, a3, q4[3]);
    uint32_t p8 = __builtin_amdgcn_cvt_pk_fp8_f32(a0, a1, 0u, false);
    p8 = __builtin_amdgcn_cvt_pk_fp8_f32(a2, a3, p8, true);
    z8[(size_t)grow * 128 + (col0 >> 2)] = p8;
  }

#pragma unroll
  for (int k = 0; k < 4; k++) { sred[t][k] = s4[k]; sred[t][4 + k] = q4[k]; }
  __syncthreads();
  if (t < 128) {
    float* p = pstat + (size_t)blockIdx.x * 1024 + (size_t)col0 * 2;
#pragma unroll
    for (int k = 0; k < 4; k++) {
      p[k * 2 + 0] = sred[t][k] + sred[t + 128][k] + sred[t + 256][k] + sred[t + 384][k];
      p[k * 2 + 1] = sred[t][4 + k] + sred[t + 128][4 + k] + sred[t + 256][4 + k] + sred[t + 384][4 + k];
    }
  }
}

// ---------- reduce partial stats -> scsh (nsl = slices per graph) ----------
__global__ void reduce_stats(const float* __restrict__ pstat, const float* __restrict__ gamma,
                             const float* __restrict__ beta, float* __restrict__ scsh, int nsl) {
  int b = blockIdx.x;                 // 32 blocks: b>>4 = g, b&15 = col group
  int g = b >> 4, cg = b & 15;
  int t = threadIdx.x;                // 256 threads
  int c = cg * 32 + (t & 31);
  int s = t >> 5;                     // 8 m-slices
  int per = nsl >> 3;
  const float2* p = (const float2*)pstat + ((size_t)(g * nsl + s * per)) * 512 + c;
  float sum = 0.f, q = 0.f;
  for (int m = 0; m < per; m++) { float2 v = p[(size_t)m * 512]; sum += v.x; q += v.y; }
  __shared__ float ls[8][64];
  ls[s][(t & 31) * 2] = sum; ls[s][(t & 31) * 2 + 1] = q;
  __syncthreads();
  if (t < 32) {
    float S = 0.f, Q = 0.f;
#pragma unroll
    for (int k = 0; k < 8; k++) { S += ls[k][t * 2]; Q += ls[k][t * 2 + 1]; }
    int cc = cg * 32 + t;
    float mu = S * (1.f / (float)NN);
    float var = fmaxf(Q * (1.f / (float)NN) - mu * mu, 0.f);
    float sc = gamma[cc] * rsqrtf(var + BN_EPS);
    scsh[g * 1024 + cc * 2] = sc;
    scsh[g * 1024 + cc * 2 + 1] = beta[cc] - mu * sc;
  }
}

// ---------- aggbn: u2 = bnrelu(z1) + mean_{nbr} bnrelu(z1_j)  (one wave per node) ----------
// R12: 8-deep double-buffered gather pipeline. R3's 8-deep failed at VGPR 72 (past the
// 64-VGPR occupancy cliff, waves halved). With fp8 uint2 payloads 8-deep costs ~+16
// VGPR -> ~56, UNDER the cliff: occupancy holds while per-wave MLP doubles.
__device__ __forceinline__ void bn_acc8_fp8(uint2 v, const f32x2* sc2, const f32x2* sh2,
                                            f32x2* acc) {
  f32x2 f[4];
  f[0] = __builtin_amdgcn_cvt_pk_f32_fp8(v.x, false);
  f[1] = __builtin_amdgcn_cvt_pk_f32_fp8(v.x, true);
  f[2] = __builtin_amdgcn_cvt_pk_f32_fp8(v.y, false);
  f[3] = __builtin_amdgcn_cvt_pk_f32_fp8(v.y, true);
#pragma unroll
  for (int i = 0; i < 4; i++) {
    f32x2 y = f[i] * sc2[i] + sh2[i];     // v_pk_fma_f32
    y.x = fmaxf(y.x, 0.f); y.y = fmaxf(y.y, 0.f);
    acc[i] += y;                          // v_pk_add_f32
  }
}

__global__ __launch_bounds__(256) void aggbn_kernel(const uint32_t* __restrict__ z8,
                             uint32_t* __restrict__ u8,
                             const int* __restrict__ csr, const int* __restrict__ offsets,
                             const float* __restrict__ scsh) {
  int wid = (blockIdx.x * 256 + threadIdx.x) >> 6;   // node id in [0, MM)
  int lane = threadIdx.x & 63;
  int g = wid >> 15, n = wid & (NN - 1);
  const int* off = offsets + g * (NN + 1);
  int e0 = off[n], e1 = off[n + 1];
  const int* ce = csr + g * EE + e0;
  const uint32_t* base8 = z8 + (size_t)g * NN * 128 + lane * 2;  // 128 u32 per fp8 row

  // self row (fp8): issue early, in flight across the gather loop
  uint2 hv8 = *(const uint2*)(base8 + (size_t)n * 128);

  const float4* ssp = (const float4*)(scsh + (size_t)g * HH * 2 + lane * 16);
  float4 ss0 = ssp[0], ss1 = ssp[1], ss2 = ssp[2], ss3 = ssp[3];
  f32x2 sc2[4], sh2[4];
  sc2[0] = f32x2{ss0.x, ss0.z}; sh2[0] = f32x2{ss0.y, ss0.w};
  sc2[1] = f32x2{ss1.x, ss1.z}; sh2[1] = f32x2{ss1.y, ss1.w};
  sc2[2] = f32x2{ss2.x, ss2.z}; sh2[2] = f32x2{ss2.y, ss2.w};
  sc2[3] = f32x2{ss3.x, ss3.z}; sh2[3] = f32x2{ss3.y, ss3.w};
  f32x2 acc2[4] = {f32x2{0.f, 0.f}, f32x2{0.f, 0.f}, f32x2{0.f, 0.f}, f32x2{0.f, 0.f}};

  int rem = e1 - e0;
  uint2 va0, va1, va2, va3, vb0, vb1, vb2, vb3;
  if (rem >= 4) {
    int a0 = ce[0], a1 = ce[1], a2 = ce[2], a3 = ce[3];
    va0 = *(const uint2*)(base8 + (size_t)a0 * 128);
    va1 = *(const uint2*)(base8 + (size_t)a1 * 128);
    va2 = *(const uint2*)(base8 + (size_t)a2 * 128);
    va3 = *(const uint2*)(base8 + (size_t)a3 * 128);
  }
  if (rem >= 8) {
    int b0 = ce[4], b1 = ce[5], b2 = ce[6], b3 = ce[7];
    vb0 = *(const uint2*)(base8 + (size_t)b0 * 128);
    vb1 = *(const uint2*)(base8 + (size_t)b1 * 128);
    vb2 = *(const uint2*)(base8 + (size_t)b2 * 128);
    vb3 = *(const uint2*)(base8 + (size_t)b3 * 128);
  }
  while (rem >= 8) {
    int na0, na1, na2, na3, nb0, nb1, nb2, nb3;
    bool ha = rem >= 12, hb = rem >= 16;
    if (ha) { na0 = ce[8];  na1 = ce[9];  na2 = ce[10]; na3 = ce[11]; }
    if (hb) { nb0 = ce[12]; nb1 = ce[13]; nb2 = ce[14]; nb3 = ce[15]; }
    bn_acc8_fp8(va0, sc2, sh2, acc2); bn_acc8_fp8(va1, sc2, sh2, acc2);
    bn_acc8_fp8(va2, sc2, sh2, acc2); bn_acc8_fp8(va3, sc2, sh2, acc2);
    if (ha) {
      va0 = *(const uint2*)(base8 + (size_t)na0 * 128);
      va1 = *(const uint2*)(base8 + (size_t)na1 * 128);
      va2 = *(const uint2*)(base8 + (size_t)na2 * 128);
      va3 = *(const uint2*)(base8 + (size_t)na3 * 128);
    }
    bn_acc8_fp8(vb0, sc2, sh2, acc2); bn_acc8_fp8(vb1, sc2, sh2, acc2);
    bn_acc8_fp8(vb2, sc2, sh2, acc2); bn_acc8_fp8(vb3, sc2, sh2, acc2);
    if (hb) {
      vb0 = *(const uint2*)(base8 + (size_t)nb0 * 128);
      vb1 = *(const uint2*)(base8 + (size_t)nb1 * 128);
      vb2 = *(const uint2*)(base8 + (size_t)nb2 * 128);
      vb3 = *(const uint2*)(base8 + (size_t)nb3 * 128);
    }
    ce += 8; rem -= 8;
  }
  int toff = 0;
  if (rem >= 4) {
    bn_acc8_fp8(va0, sc2, sh2, acc2); bn_acc8_fp8(va1, sc2, sh2, acc2);
    bn_acc8_fp8(va2, sc2, sh2, acc2); bn_acc8_fp8(va3, sc2, sh2, acc2);
    rem -= 4; toff = 4;
  }
  for (int i = 0; i < rem; i++) {
    int s = ce[toff + i];
    uint2 v = *(const uint2*)(base8 + (size_t)s * 128);
    bn_acc8_fp8(v, sc2, sh2, acc2);
  }

  int deg = e1 - e0;
  float inv = (deg > 0) ? 1.f / (float)deg : 0.f;
  f32x2 h01 = __builtin_amdgcn_cvt_pk_f32_fp8(hv8.x, false);
  f32x2 h23 = __builtin_amdgcn_cvt_pk_f32_fp8(hv8.x, true);
  f32x2 h45 = __builtin_amdgcn_cvt_pk_f32_fp8(hv8.y, false);
  f32x2 h67 = __builtin_amdgcn_cvt_pk_f32_fp8(hv8.y, true);
  f32x2 hs[4] = {h01, h23, h45, h67};
  float o[8];
#pragma unroll
  for (int i = 0; i < 4; i++) {
    f32x2 y = hs[i] * sc2[i] + sh2[i];
    o[2 * i]     = fmaxf(y.x, 0.f) + acc2[i].x * inv;
    o[2 * i + 1] = fmaxf(y.y, 0.f) + acc2[i].y * inv;
  }
  uint32_t q0 = __builtin_amdgcn_cvt_pk_fp8_f32(o[0], o[1], 0u, false);
  q0 = __builtin_amdgcn_cvt_pk_fp8_f32(o[2], o[3], q0, true);
  uint32_t q1 = __builtin_amdgcn_cvt_pk_fp8_f32(o[4], o[5], 0u, false);
  q1 = __builtin_amdgcn_cvt_pk_fp8_f32(o[6], o[7], q1, true);
  uint2 ov; ov.x = q0; ov.y = q1;
  *(uint2*)(u8 + (size_t)wid * 128 + lane * 2) = ov;
}

// ---------- GEMM (fp8 x fp8): Z2[M,512](fp8) = A8[M,512] @ Wt8^T + bias ----------
// R11 shape (128x128/256t, b128 reads, 0-conflict pattern); fp8 out; fused stats.
__global__ __launch_bounds__(256) void gemm_kernel(const uint8_t* __restrict__ A8,
                                                   const uint8_t* __restrict__ Bt8,
                                                   const float* __restrict__ bias,
                                                   uint8_t* __restrict__ Z2,
                                                   float* __restrict__ pstat) {
  __shared__ __align__(16) char lds[33792];   // staging 32KB; sC 128x132 u16 = 33792B
  uint8_t* sA = (uint8_t*)lds;                // 128 rows x 128B
  uint8_t* sB = (uint8_t*)lds + 16384;
  const int tid = threadIdx.x;
  const int wave = tid >> 6;
  const int lane = tid & 63;
  const int bid = blockIdx.x;                 // 2048 blocks
  const int xcd = bid & 7;
  const int l = bid >> 3;
  const int nb = l & 3;
  const int mb = xcd * 64 + (l >> 2);
  const int m0 = mb * 128;
  const int n0 = nb * 128;
  const int fm = lane & 15;
  const int quad = lane >> 4;
  const int wr = wave >> 1, wc = wave & 1;

  const int sr = lane >> 3;                   // staging row within wave-group
  const int slot = lane & 7;                  // 16B slot within 128B row

  f32x4 acc[4][4] = {};
  for (int k0 = 0; k0 < HH; k0 += 128) {
    __syncthreads();
#pragma unroll
    for (int t = 0; t < 4; t++) {
      int R = t * 32 + wave * 8 + sr;
      int ksw = (slot ^ (R & 7)) * 16;
      gl2lds16(A8 + (size_t)(m0 + R) * HH + k0 + ksw, sA + R * 128 + slot * 16);
      gl2lds16(Bt8 + (size_t)(n0 + R) * HH + k0 + ksw, sB + R * 128 + slot * 16);
    }
    __syncthreads();
#pragma unroll
    for (int s2 = 0; s2 < 2; s2++) {
      const int k16 = s2 * 4 + quad;          // 16B granule 0..7
      longx2 a[4], b[4];
#pragma unroll
      for (int i = 0; i < 4; i++) {
        int r = wr * 64 + i * 16 + fm;
        a[i] = *(const longx2*)(sA + r * 128 + ((k16 ^ (r & 7)) * 16));
      }
#pragma unroll
      for (int j = 0; j < 4; j++) {
        int r = wc * 64 + j * 16 + fm;
        b[j] = *(const longx2*)(sB + r * 128 + ((k16 ^ (r & 7)) * 16));
      }
#pragma unroll
      for (int i = 0; i < 4; i++)
#pragma unroll
        for (int j = 0; j < 4; j++) {
          acc[i][j] = __builtin_amdgcn_mfma_f32_16x16x32_fp8_fp8(a[i][0], b[j][0], acc[i][j], 0, 0, 0);
          acc[i][j] = __builtin_amdgcn_mfma_f32_16x16x32_fp8_fp8(a[i][1], b[j][1], acc[i][j], 0, 0, 0);
        }
    }
  }

  // ---- epilogue ----
  float bj4[4];
#pragma unroll
  for (int j = 0; j < 4; j++) bj4[j] = bias[n0 + wc * 64 + j * 16 + fm];

  __syncthreads();                        // staging LDS dead
  float* ls = (float*)lds;                // 128 cols x 2 stats (1 KB)
  if (tid < 256) ls[tid] = 0.f;
  __syncthreads();
#pragma unroll
  for (int j = 0; j < 4; j++) {
    int colloc = wc * 64 + j * 16 + fm;
    float sj = 0.f, qj = 0.f;
#pragma unroll
    for (int i = 0; i < 4; i++)
#pragma unroll
      for (int r = 0; r < 4; r++) {
        float f = acc[i][j][r] + bj4[j];
        sj += f; qj = fmaf(f, f, qj);
      }
    atomicAdd(&ls[colloc * 2], sj);
    atomicAdd(&ls[colloc * 2 + 1], qj);
  }
  __syncthreads();
  if (tid < 128) {
    float* p = pstat + (size_t)mb * 1024 + (size_t)(n0 + tid) * 2;
    p[0] = ls[tid * 2];
    p[1] = ls[tid * 2 + 1];
  }
  __syncthreads();

  // bounce acc -> sC bf16 (stride 132: rows shift 2 banks), fp8-pack, 16B row stores
  uint16_t* sC = (uint16_t*)lds;          // 128 x 132 u16 = 33792 B
#pragma unroll
  for (int j = 0; j < 4; j++) {
    int col = wc * 64 + j * 16 + fm;
#pragma unroll
    for (int i = 0; i < 4; i++) {
      int rb = wr * 64 + i * 16 + quad * 4;
#pragma unroll
      for (int r = 0; r < 4; r++)
        sC[(rb + r) * 132 + col] = (uint16_t)f2bf_u(acc[i][j][r] + bj4[j]);
    }
  }
  __syncthreads();
#pragma unroll
  for (int r2 = 0; r2 < 4; r2++) {
    int row = r2 * 32 + (tid >> 3);
    int oc16 = (tid & 7) * 16;            // 16 cols per 16B store
    uint4 va = *(const uint4*)(sC + row * 132 + oc16);
    uint4 vb = *(const uint4*)(sC + row * 132 + oc16 + 8);
    uint32_t wv[8] = {va.x, va.y, va.z, va.w, vb.x, vb.y, vb.z, vb.w};
    uint4 o8;
    uint32_t* op = (uint32_t*)&o8;
#pragma unroll
    for (int q = 0; q < 4; q++) {
      uint32_t p8 = __builtin_amdgcn_cvt_pk_fp8_f32(bflo(wv[2 * q]), bfhi(wv[2 * q]), 0u, false);
      p8 = __builtin_amdgcn_cvt_pk_fp8_f32(bflo(wv[2 * q + 1]), bfhi(wv[2 * q + 1]), p8, true);
      op[q] = p8;
    }
    *(uint4*)(Z2 + (size_t)(m0 + row) * HH + n0 + oc16) = o8;
  }
}

// ---------- BN+ReLU + per-graph-id readout sums (fp8 z2 in; h2 never materialized) ----------
__global__ void bn2_readout(const uint32_t* __restrict__ z2, const float* __restrict__ scsh,
                            const int* __restrict__ gids1, const int* __restrict__ gids2,
                            float* __restrict__ readout, float* __restrict__ cnt) {
  int blk = blockIdx.x;                // 512 blocks x 128 rows (within one 512-row subgraph)
  int r0 = blk * 128;
  int g = r0 >> 15;
  int lr = r0 & (NN - 1);
  int gid = (g ? gids2 : gids1)[lr];
  int t = threadIdx.x;                 // 256: cg = u32 col group (4 cols), rh = row half
  int cg = t & 127, rh = t >> 7;
  const float* ss = scsh + (size_t)g * HH * 2 + cg * 8;
  float4 s0 = *(const float4*)ss, s1 = *(const float4*)(ss + 4);
  f32x2 sc01 = f32x2{s0.x, s0.z}, sh01 = f32x2{s0.y, s0.w};
  f32x2 sc23 = f32x2{s1.x, s1.z}, sh23 = f32x2{s1.y, s1.w};
  const uint32_t* p = z2 + (size_t)(r0 + rh * 64) * 128 + cg;
  f32x2 a01 = f32x2{0.f, 0.f}, a23 = f32x2{0.f, 0.f};
  for (int r = 0; r < 64; r++) {
    uint32_t w = p[(size_t)r * 128];
    f32x2 f01 = __builtin_amdgcn_cvt_pk_f32_fp8(w, false);
    f32x2 f23 = __builtin_amdgcn_cvt_pk_f32_fp8(w, true);
    f32x2 y0 = f01 * sc01 + sh01;
    f32x2 y1 = f23 * sc23 + sh23;
    y0.x = fmaxf(y0.x, 0.f); y0.y = fmaxf(y0.y, 0.f);
    y1.x = fmaxf(y1.x, 0.f); y1.y = fmaxf(y1.y, 0.f);
    a01 += y0; a23 += y1;
  }
  __shared__ float sr2[128][4];
  if (rh) { sr2[cg][0] = a01.x; sr2[cg][1] = a01.y; sr2[cg][2] = a23.x; sr2[cg][3] = a23.y; }
  __syncthreads();
  if (!rh) {
    float* ro = readout + ((size_t)g * BB + gid) * HH;
    atomicAdd(&ro[cg * 4 + 0], a01.x + sr2[cg][0]);
    atomicAdd(&ro[cg * 4 + 1], a01.y + sr2[cg][1]);
    atomicAdd(&ro[cg * 4 + 2], a23.x + sr2[cg][2]);
    atomicAdd(&ro[cg * 4 + 3], a23.y + sr2[cg][3]);
  }
  if (t == 0) atomicAdd(&cnt[g * BB + gid], 128.f);
}

// ---------- head: concat -> fc relu -> fc2 sigmoid ----------
__global__ void final_kernel(const float* __restrict__ readout, const float* __restrict__ cnt,
                             const float* __restrict__ Wfc, const float* __restrict__ bfc,
                             const float* __restrict__ Wfc2, const float* __restrict__ bfc2,
                             float* __restrict__ out) {
  __shared__ float x[1024];
  __shared__ float red[256];
  int b = blockIdx.x, t = threadIdx.x;
  for (int i = t; i < 1024; i += 256) {
    int g = i >> 9, c = i & 511;
    float cc = cnt[g * BB + b];
    x[i] = readout[((size_t)g * BB + b) * HH + c] / fmaxf(cc, 1.f);
  }
  __syncthreads();
  float a0 = 0.f, a1 = 0.f, a2 = 0.f, a3 = 0.f;   // 4-way ILP: break the dep chain
  for (int i = 0; i < 1024; i += 4) {
    a0 = fmaf(x[i],     Wfc[(size_t)i * 256 + t],       a0);
    a1 = fmaf(x[i + 1], Wfc[(size_t)(i + 1) * 256 + t], a1);
    a2 = fmaf(x[i + 2], Wfc[(size_t)(i + 2) * 256 + t], a2);
    a3 = fmaf(x[i + 3], Wfc[(size_t)(i + 3) * 256 + t], a3);
  }
  float acc = bfc[t] + ((a0 + a1) + (a2 + a3));
  red[t] = fmaxf(acc, 0.f) * Wfc2[t];
  __syncthreads();
  for (int s = 128; s > 0; s >>= 1) {
    if (t < s) red[t] += red[t + s];
    __syncthreads();
  }
  if (t == 0) out[b] = 1.f / (1.f + expf(-(red[0] + bfc2[0])));
}

// ---------- launch ----------
extern "C" void kernel_launch(void* const* d_in, const int* in_sizes, int n_in,
                              void* d_out, int out_size, void* d_ws, size_t ws_size,
                              hipStream_t stream) {
  const float* x1 = (const float*)d_in[0];
  const float* x2 = (const float*)d_in[1];
  const int* src1 = (const int*)d_in[2];
  const int* dst1 = (const int*)d_in[3];
  const int* src2 = (const int*)d_in[4];
  const int* dst2 = (const int*)d_in[5];
  const int* gids1 = (const int*)d_in[6];
  const int* gids2 = (const int*)d_in[7];
  const float* Wi = (const float*)d_in[8];
  const float* bi = (const float*)d_in[9];
  const float* W1 = (const float*)d_in[10];
  const float* b1 = (const float*)d_in[11];
  const float* W2 = (const float*)d_in[12];
  const float* b2 = (const float*)d_in[13];
  const float* gamma1 = (const float*)d_in[14];
  const float* beta1 = (const float*)d_in[15];
  const float* gamma2 = (const float*)d_in[16];
  const float* beta2 = (const float*)d_in[17];
  const float* Wfc = (const float*)d_in[18];
  const float* bfc = (const float*)d_in[19];
  const float* Wfc2 = (const float*)d_in[20];
  const float* bfc2 = (const float*)d_in[21];
  float* out = (float*)d_out;

  // workspace layout (256B-aligned slabs)
  size_t off = 0;
  auto alloc = [&](size_t bytes) -> void* {
    void* p = (char*)d_ws + off;
    off += (bytes + 255) & ~(size_t)255;
    return p;
  };
  uint32_t* z8 = (uint32_t*)alloc((size_t)MM * HH);          // fp8 z1 (32 MB)
  uint32_t* u8 = (uint32_t*)alloc((size_t)MM * HH);          // fp8 u2 (GEMM A operand)
  uint8_t* z2o = (uint8_t*)alloc((size_t)MM * HH);           // fp8 z2 (GEMM out, 32 MB)
  uint32_t* Wt8 = (uint32_t*)alloc((size_t)HH * HH);         // fp8 W2^T (256 KB)
  float* Wf = (float*)alloc((size_t)(DIN + 1) * HH * 4);
  int* csr = (int*)alloc((size_t)2 * EE * 4);
  int* offsets = (int*)alloc((size_t)2 * (NN + 1) * 4);
  int* cursor = (int*)alloc((size_t)2 * NN * 4);
  float* pbuf1 = (float*)alloc((size_t)512 * 512 * 2 * 4);   // z1 per-block col stats
  float* pbuf2 = (float*)alloc((size_t)512 * 512 * 2 * 4);   // gemm per-mtile col stats
  size_t zero_begin = off;
  int* deg_cnt = (int*)alloc((size_t)2 * NN * 4);
  float* readout = (float*)alloc((size_t)2 * BB * HH * 4);
  float* cnt = (float*)alloc((size_t)2 * BB * 4);
  size_t zero_end = off;
  float* scsh1 = (float*)alloc((size_t)2 * HH * 2 * 4);
  float* scsh2 = (float*)alloc((size_t)2 * HH * 2 * 4);
  (void)ws_size; (void)in_sizes; (void)n_in; (void)out_size;

  hipMemsetAsync((char*)d_ws + zero_begin, 0, zero_end - zero_begin, stream);

  // weights + CSR build (deg + W2->fp8 transpose + fold in one launch)
  prep_deg_kernel<<<2304 + 42, 256, 0, stream>>>(dst1, dst2, deg_cnt, W2, Wt8, Wi, bi, W1, Wf);
  scan_kernel<<<2, 1024, 0, stream>>>(deg_cnt, offsets, cursor);
  scatter_kernel<<<2048, 256, 0, stream>>>(src1, dst1, src2, dst2, cursor, csr);

  // layer 1 (GEMM folded, xagg fused): z1 -> z8 (fp8) + fused stats -> reduce -> scsh1
  z1_kernel<<<MM / 128, 512, 0, stream>>>(x1, x2, csr, offsets, Wf, b1, z8, pbuf1);
  reduce_stats<<<32, 256, 0, stream>>>(pbuf1, gamma1, beta1, scsh1, 256);

  // layer 2: aggbn(z8)->u8(fp8) ; fp8 gemm -> z2(fp8) (+fused stats) ; reduce ; bn2+readout
  aggbn_kernel<<<MM / 4, 256, 0, stream>>>(z8, u8, csr, offsets, scsh1);
  gemm_kernel<<<2048, 256, 0, stream>>>((const uint8_t*)u8, (const uint8_t*)Wt8, b2, z2o, pbuf2);
  reduce_stats<<<32, 256, 0, stream>>>(pbuf2, gamma2, beta2, scsh2, 256);
  bn2_readout<<<512, 256, 0, stream>>>((const uint32_t*)z2o, scsh2, gids1, gids2, readout, cnt);

  // head
  final_kernel<<<BB, 256, 0, stream>>>(readout, cnt, Wfc, bfc, Wfc2, bfc2, out);
}

// Round 13
// 374.421 us; speedup vs baseline: 1.0881x; 1.0881x over previous
//
#include <hip/hip_runtime.h>
#include <hip/hip_bf16.h>
#include <cstdint>

// Problem constants (fixed by the reference harness)
#define NN 32768      // nodes per graph
#define EE 262144     // edges per graph
#define MM 65536      // 2*NN combined rows
#define HH 512
#define BB 64
#define DIN 20
#define BN_EPS 1e-5f

// ---------- bf16 helpers (bit-level, fast) ----------
__device__ __forceinline__ float bflo(uint32_t w) { return __builtin_bit_cast(float, w << 16); }
__device__ __forceinline__ float bfhi(uint32_t w) { return __builtin_bit_cast(float, w & 0xffff0000u); }
__device__ __forceinline__ uint32_t f2bf_u(float f) {
  uint32_t u = __builtin_bit_cast(uint32_t, f);
  return (u + 0x7fffu + ((u >> 16) & 1u)) >> 16;   // RTNE
}
__device__ __forceinline__ uint32_t pack2(float lo, float hi) {
  return f2bf_u(lo) | (f2bf_u(hi) << 16);
}

typedef float f32x4 __attribute__((ext_vector_type(4)));
typedef float f32x2 __attribute__((ext_vector_type(2)));
typedef long longx2 __attribute__((ext_vector_type(2)));

__device__ __forceinline__ void gl2lds16(const void* g, void* l) {
  __builtin_amdgcn_global_load_lds(
      (const __attribute__((address_space(1))) void*)g,
      (__attribute__((address_space(3))) void*)l, 16, 0, 0);
}

// ---------- prep+deg merged: deg histogram AND W2 -> fp8 transposed AND Wf fold ----------
__global__ void prep_deg_kernel(const int* __restrict__ dst1, const int* __restrict__ dst2,
                                int* __restrict__ deg_cnt,
                                const float* __restrict__ W2, uint32_t* __restrict__ Wt8,
                                const float* __restrict__ Wi, const float* __restrict__ bi,
                                const float* __restrict__ W1, float* __restrict__ Wf) {
  int bid = blockIdx.x;
  if (bid < 2048) {
    int e = bid * 256 + threadIdx.x;            // < 2*EE
    int g = e >> 18, le = e & 0x3ffff;
    int d = (g ? dst2 : dst1)[le];
    atomicAdd(&deg_cnt[g * NN + d], 1);
  } else if (bid < 2304) {
    // W2 [k][n] fp32 -> Wt8 [n][k] fp8-e4m3 (fp8 GEMM B-operand)
    int idx = (bid - 2048) * 256 + threadIdx.x; // < 512*128
    int n = idx >> 7, k4 = idx & 127;
    int k = k4 * 4;
    float w0 = W2[(size_t)k * HH + n];
    float w1 = W2[(size_t)(k + 1) * HH + n];
    float w2v = W2[(size_t)(k + 2) * HH + n];
    float w3 = W2[(size_t)(k + 3) * HH + n];
    uint32_t p = __builtin_amdgcn_cvt_pk_fp8_f32(w0, w1, 0u, false);
    p = __builtin_amdgcn_cvt_pk_fp8_f32(w2v, w3, p, true);
    Wt8[(size_t)n * 128 + k4] = p;
  } else {
    int idx = (bid - 2304) * 256 + threadIdx.x; // < 21*512
    if (idx >= 21 * 512) return;
    int k = idx >> 9, n = idx & 511;
    float s = 0.f;
    if (k < 20) {
      const float* wr = Wi + (size_t)k * HH;
      for (int j = 0; j < HH; j++) s = fmaf(wr[j], W1[(size_t)j * HH + n], s);
    } else {
      for (int j = 0; j < HH; j++) s = fmaf(bi[j], W1[(size_t)j * HH + n], s);
    }
    Wf[idx] = s;
  }
}

// ---------- CSR build ----------
__global__ void scan_kernel(const int* __restrict__ deg_cnt, int* __restrict__ offsets,
                            int* __restrict__ cursor) {
  int g = blockIdx.x;
  const int* d = deg_cnt + g * NN;
  int* off = offsets + g * (NN + 1);
  int* cur = cursor + g * NN;
  int t = threadIdx.x;                          // 1024 threads
  int base = t * 32;
  int loc[32]; int s = 0;
#pragma unroll
  for (int i = 0; i < 32; i++) { loc[i] = d[base + i]; s += loc[i]; }
  __shared__ int sm[1024];
  sm[t] = s; __syncthreads();
  for (int ofs = 1; ofs < 1024; ofs <<= 1) {
    int v = sm[t];
    int add = (t >= ofs) ? sm[t - ofs] : 0;
    __syncthreads();
    sm[t] = v + add;
    __syncthreads();
  }
  int run = (t == 0) ? 0 : sm[t - 1];
#pragma unroll
  for (int i = 0; i < 32; i++) { off[base + i] = run; cur[base + i] = run; run += loc[i]; }
  if (t == 1023) off[NN] = run;
}

__global__ void scatter_kernel(const int* __restrict__ src1, const int* __restrict__ dst1,
                               const int* __restrict__ src2, const int* __restrict__ dst2,
                               int* __restrict__ cursor, int* __restrict__ csr) {
  int e = blockIdx.x * 256 + threadIdx.x;       // < 2*EE
  int g = e >> 18, le = e & 0x3ffff;
  int d = (g ? dst2 : dst1)[le];
  int s = (g ? src2 : src1)[le];
  int pos = atomicAdd(&cursor[g * NN + d], 1);
  csr[g * EE + pos] = s;
}

// ---------- z1 (xagg fused): z1 = xa@Wf + bf*bvec + b1, fp8 output ONLY ----------
// Edge-parallel gather (4 lanes/row), 512-thread blocks (R9 best-measured).
__global__ __launch_bounds__(512) void z1_kernel(const float* __restrict__ x1,
                          const float* __restrict__ x2,
                          const int* __restrict__ csr, const int* __restrict__ offsets,
                          const float* __restrict__ Wf, const float* __restrict__ b1,
                          uint32_t* __restrict__ z8, float* __restrict__ pstat) {
  __shared__ float xas[128][21];    // 21-pad: conflict-free writes
  __shared__ float sred[512][8];
  int t = threadIdx.x;
  int r0 = blockIdx.x * 128;        // 512 blocks x 128 rows; never straddles graphs
  int g = r0 >> 15;
  const float* xg = g ? x2 : x1;
  const int* off = offsets + g * (NN + 1);
  const int* cs = csr + g * EE;

  // ---- phase 1: xa = x + mean_nbr x (4 lanes/row, edge-parallel) ----
  {
    int row = t >> 2;               // 128 rows
    int q = t & 3;
    int n = (r0 + row) & (NN - 1);
    int e0 = off[n], e1 = off[n + 1];
    float4 a4[5] = {};
    for (int e = e0 + q; e < e1; e += 4) {
      const float4* xr = (const float4*)(xg + (size_t)cs[e] * DIN);
#pragma unroll
      for (int k = 0; k < 5; k++) {
        float4 v = xr[k];
        a4[k].x += v.x; a4[k].y += v.y; a4[k].z += v.z; a4[k].w += v.w;
      }
    }
    // butterfly across the 4 lanes of this row (all lanes end with full sums)
#pragma unroll
    for (int k = 0; k < 5; k++) {
      a4[k].x += __shfl_xor(a4[k].x, 1); a4[k].y += __shfl_xor(a4[k].y, 1);
      a4[k].z += __shfl_xor(a4[k].z, 1); a4[k].w += __shfl_xor(a4[k].w, 1);
      a4[k].x += __shfl_xor(a4[k].x, 2); a4[k].y += __shfl_xor(a4[k].y, 2);
      a4[k].z += __shfl_xor(a4[k].z, 2); a4[k].w += __shfl_xor(a4[k].w, 2);
    }
    if (q == 0) {
      float inv = (e1 > e0) ? 1.f / (float)(e1 - e0) : 0.f;
      const float4* xs = (const float4*)(xg + (size_t)n * DIN);
#pragma unroll
      for (int k = 0; k < 5; k++) {
        float4 v = xs[k];
        xas[row][k * 4 + 0] = fmaf(a4[k].x, inv, v.x);
        xas[row][k * 4 + 1] = fmaf(a4[k].y, inv, v.y);
        xas[row][k * 4 + 2] = fmaf(a4[k].z, inv, v.z);
        xas[row][k * 4 + 3] = fmaf(a4[k].w, inv, v.w);
      }
    }
  }
  __syncthreads();

  // ---- phase 2: GEMV over 512 cols (128 col-threads x 4 row-groups) ----
  int col0 = (t & 127) * 4;
  int rq = t >> 7;                  // wave-uniform

  float w[DIN][4];
#pragma unroll
  for (int k = 0; k < DIN; k++) {
    float4 wv = *(const float4*)(Wf + (size_t)k * HH + col0);
    w[k][0] = wv.x; w[k][1] = wv.y; w[k][2] = wv.z; w[k][3] = wv.w;
  }
  float4 bvv = *(const float4*)(Wf + (size_t)DIN * HH + col0);   // bi @ W1
  float4 b1v = *(const float4*)(b1 + col0);

  float s4[4] = {0.f, 0.f, 0.f, 0.f}, q4[4] = {0.f, 0.f, 0.f, 0.f};
  for (int rr = 0; rr < 32; rr++) {
    int row = rr * 4 + rq;
    int grow = r0 + row;
    int n = grow & (NN - 1);
    float bf = (off[n + 1] - off[n] > 0) ? 2.f : 1.f;   // wave-uniform
    float a0 = fmaf(bvv.x, bf, b1v.x), a1 = fmaf(bvv.y, bf, b1v.y);
    float a2 = fmaf(bvv.z, bf, b1v.z), a3 = fmaf(bvv.w, bf, b1v.w);
#pragma unroll
    for (int k = 0; k < DIN; k++) {
      float xv = xas[row][k];       // uniform addr within wave -> LDS broadcast
      a0 = fmaf(xv, w[k][0], a0);
      a1 = fmaf(xv, w[k][1], a1);
      a2 = fmaf(xv, w[k][2], a2);
      a3 = fmaf(xv, w[k][3], a3);
    }
    s4[0] += a0; q4[0] = fmaf(a0, a0, q4[0]);
    s4[1] += a1; q4[1] = fmaf(a1, a1, q4[1]);
    s4[2] += a2; q4[2] = fmaf(a2, a2, q4[2]);
    s4[3] += a3; q4[3] = fmaf(a3, a3, q4[3]);
    uint32_t p8 = __builtin_amdgcn_cvt_pk_fp8_f32(a0, a1, 0u, false);
    p8 = __builtin_amdgcn_cvt_pk_fp8_f32(a2, a3, p8, true);
    z8[(size_t)grow * 128 + (col0 >> 2)] = p8;
  }

#pragma unroll
  for (int k = 0; k < 4; k++) { sred[t][k] = s4[k]; sred[t][4 + k] = q4[k]; }
  __syncthreads();
  if (t < 128) {
    float* p = pstat + (size_t)blockIdx.x * 1024 + (size_t)col0 * 2;
#pragma unroll
    for (int k = 0; k < 4; k++) {
      p[k * 2 + 0] = sred[t][k] + sred[t + 128][k] + sred[t + 256][k] + sred[t + 384][k];
      p[k * 2 + 1] = sred[t][4 + k] + sred[t + 128][4 + k] + sred[t + 256][4 + k] + sred[t + 384][4 + k];
    }
  }
}

// ---------- reduce partial stats -> scsh (nsl = slices per graph) ----------
__global__ void reduce_stats(const float* __restrict__ pstat, const float* __restrict__ gamma,
                             const float* __restrict__ beta, float* __restrict__ scsh, int nsl) {
  int b = blockIdx.x;                 // 32 blocks: b>>4 = g, b&15 = col group
  int g = b >> 4, cg = b & 15;
  int t = threadIdx.x;                // 256 threads
  int c = cg * 32 + (t & 31);
  int s = t >> 5;                     // 8 m-slices
  int per = nsl >> 3;
  const float2* p = (const float2*)pstat + ((size_t)(g * nsl + s * per)) * 512 + c;
  float sum = 0.f, q = 0.f;
  for (int m = 0; m < per; m++) { float2 v = p[(size_t)m * 512]; sum += v.x; q += v.y; }
  __shared__ float ls[8][64];
  ls[s][(t & 31) * 2] = sum; ls[s][(t & 31) * 2 + 1] = q;
  __syncthreads();
  if (t < 32) {
    float S = 0.f, Q = 0.f;
#pragma unroll
    for (int k = 0; k < 8; k++) { S += ls[k][t * 2]; Q += ls[k][t * 2 + 1]; }
    int cc = cg * 32 + t;
    float mu = S * (1.f / (float)NN);
    float var = fmaxf(Q * (1.f / (float)NN) - mu * mu, 0.f);
    float sc = gamma[cc] * rsqrtf(var + BN_EPS);
    scsh[g * 1024 + cc * 2] = sc;
    scsh[g * 1024 + cc * 2 + 1] = beta[cc] - mu * sc;
  }
}

// ---------- aggbn: u2 = bnrelu(z1) + mean_{nbr} bnrelu(z1_j)  (one wave per node) ----------
// R13: reverted to the R11-measured best (4-deep, packed f32x2 math, VGPR 40,
// occupancy ~48%). Deep pipelines lose 3/3 times (R2/R3/R12): 8-deep forces VGPR
// past the 64 cliff (R12: 72 VGPR -> occupancy 25%, 92us). The fp8 gather path is
// at its latency/line-rate co-wall at ~57-60us.
__device__ __forceinline__ void bn_acc8_fp8(uint2 v, const f32x2* sc2, const f32x2* sh2,
                                            f32x2* acc) {
  f32x2 f[4];
  f[0] = __builtin_amdgcn_cvt_pk_f32_fp8(v.x, false);
  f[1] = __builtin_amdgcn_cvt_pk_f32_fp8(v.x, true);
  f[2] = __builtin_amdgcn_cvt_pk_f32_fp8(v.y, false);
  f[3] = __builtin_amdgcn_cvt_pk_f32_fp8(v.y, true);
#pragma unroll
  for (int i = 0; i < 4; i++) {
    f32x2 y = f[i] * sc2[i] + sh2[i];     // v_pk_fma_f32
    y.x = fmaxf(y.x, 0.f); y.y = fmaxf(y.y, 0.f);
    acc[i] += y;                          // v_pk_add_f32
  }
}

__global__ __launch_bounds__(256) void aggbn_kernel(const uint32_t* __restrict__ z8,
                             uint32_t* __restrict__ u8,
                             const int* __restrict__ csr, const int* __restrict__ offsets,
                             const float* __restrict__ scsh) {
  int wid = (blockIdx.x * 256 + threadIdx.x) >> 6;   // node id in [0, MM)
  int lane = threadIdx.x & 63;
  int g = wid >> 15, n = wid & (NN - 1);
  const int* off = offsets + g * (NN + 1);
  int e0 = off[n], e1 = off[n + 1];
  const int* cs = csr + g * EE;
  const uint32_t* base8 = z8 + (size_t)g * NN * 128 + lane * 2;  // 128 u32 per fp8 row

  // self row (fp8): issue early, in flight across the gather loop
  uint2 hv8 = *(const uint2*)(base8 + (size_t)n * 128);

  const float4* ssp = (const float4*)(scsh + (size_t)g * HH * 2 + lane * 16);
  float4 ss0 = ssp[0], ss1 = ssp[1], ss2 = ssp[2], ss3 = ssp[3];
  f32x2 sc2[4], sh2[4];
  sc2[0] = f32x2{ss0.x, ss0.z}; sh2[0] = f32x2{ss0.y, ss0.w};
  sc2[1] = f32x2{ss1.x, ss1.z}; sh2[1] = f32x2{ss1.y, ss1.w};
  sc2[2] = f32x2{ss2.x, ss2.z}; sh2[2] = f32x2{ss2.y, ss2.w};
  sc2[3] = f32x2{ss3.x, ss3.z}; sh2[3] = f32x2{ss3.y, ss3.w};
  f32x2 acc2[4] = {f32x2{0.f, 0.f}, f32x2{0.f, 0.f}, f32x2{0.f, 0.f}, f32x2{0.f, 0.f}};

  int e = e0;
  int rem = e1 - e0;
  int s0 = 0, s1 = 0, s2 = 0, s3 = 0;
  if (rem >= 4) { s0 = cs[e]; s1 = cs[e + 1]; s2 = cs[e + 2]; s3 = cs[e + 3]; }
  while (rem >= 4) {
    uint2 v0 = *(const uint2*)(base8 + (size_t)s0 * 128);
    uint2 v1 = *(const uint2*)(base8 + (size_t)s1 * 128);
    uint2 v2 = *(const uint2*)(base8 + (size_t)s2 * 128);
    uint2 v3 = *(const uint2*)(base8 + (size_t)s3 * 128);
    e += 4; rem -= 4;
    if (rem >= 4) { s0 = cs[e]; s1 = cs[e + 1]; s2 = cs[e + 2]; s3 = cs[e + 3]; }
    bn_acc8_fp8(v0, sc2, sh2, acc2);
    bn_acc8_fp8(v1, sc2, sh2, acc2);
    bn_acc8_fp8(v2, sc2, sh2, acc2);
    bn_acc8_fp8(v3, sc2, sh2, acc2);
  }
  for (; rem > 0; rem--, e++) {
    int s = cs[e];
    uint2 v = *(const uint2*)(base8 + (size_t)s * 128);
    bn_acc8_fp8(v, sc2, sh2, acc2);
  }

  float inv = (e1 > e0) ? 1.f / (float)(e1 - e0) : 0.f;
  f32x2 h01 = __builtin_amdgcn_cvt_pk_f32_fp8(hv8.x, false);
  f32x2 h23 = __builtin_amdgcn_cvt_pk_f32_fp8(hv8.x, true);
  f32x2 h45 = __builtin_amdgcn_cvt_pk_f32_fp8(hv8.y, false);
  f32x2 h67 = __builtin_amdgcn_cvt_pk_f32_fp8(hv8.y, true);
  f32x2 hs[4] = {h01, h23, h45, h67};
  float o[8];
#pragma unroll
  for (int i = 0; i < 4; i++) {
    f32x2 y = hs[i] * sc2[i] + sh2[i];
    o[2 * i]     = fmaxf(y.x, 0.f) + acc2[i].x * inv;
    o[2 * i + 1] = fmaxf(y.y, 0.f) + acc2[i].y * inv;
  }
  uint32_t q0 = __builtin_amdgcn_cvt_pk_fp8_f32(o[0], o[1], 0u, false);
  q0 = __builtin_amdgcn_cvt_pk_fp8_f32(o[2], o[3], q0, true);
  uint32_t q1 = __builtin_amdgcn_cvt_pk_fp8_f32(o[4], o[5], 0u, false);
  q1 = __builtin_amdgcn_cvt_pk_fp8_f32(o[6], o[7], q1, true);
  uint2 ov; ov.x = q0; ov.y = q1;
  *(uint2*)(u8 + (size_t)wid * 128 + lane * 2) = ov;
}

// ---------- GEMM (fp8 x fp8): Z2[M,512](fp8) = A8[M,512] @ Wt8^T + bias ----------
// R11 shape (128x128/256t, b128 reads, 0-conflict pattern); fp8 out; fused stats.
__global__ __launch_bounds__(256) void gemm_kernel(const uint8_t* __restrict__ A8,
                                                   const uint8_t* __restrict__ Bt8,
                                                   const float* __restrict__ bias,
                                                   uint8_t* __restrict__ Z2,
                                                   float* __restrict__ pstat) {
  __shared__ __align__(16) char lds[33792];   // staging 32KB; sC 128x132 u16 = 33792B
  uint8_t* sA = (uint8_t*)lds;                // 128 rows x 128B
  uint8_t* sB = (uint8_t*)lds + 16384;
  const int tid = threadIdx.x;
  const int wave = tid >> 6;
  const int lane = tid & 63;
  const int bid = blockIdx.x;                 // 2048 blocks
  const int xcd = bid & 7;
  const int l = bid >> 3;
  const int nb = l & 3;
  const int mb = xcd * 64 + (l >> 2);
  const int m0 = mb * 128;
  const int n0 = nb * 128;
  const int fm = lane & 15;
  const int quad = lane >> 4;
  const int wr = wave >> 1, wc = wave & 1;

  const int sr = lane >> 3;                   // staging row within wave-group
  const int slot = lane & 7;                  // 16B slot within 128B row

  f32x4 acc[4][4] = {};
  for (int k0 = 0; k0 < HH; k0 += 128) {
    __syncthreads();
#pragma unroll
    for (int t = 0; t < 4; t++) {
      int R = t * 32 + wave * 8 + sr;
      int ksw = (slot ^ (R & 7)) * 16;
      gl2lds16(A8 + (size_t)(m0 + R) * HH + k0 + ksw, sA + R * 128 + slot * 16);
      gl2lds16(Bt8 + (size_t)(n0 + R) * HH + k0 + ksw, sB + R * 128 + slot * 16);
    }
    __syncthreads();
#pragma unroll
    for (int s2 = 0; s2 < 2; s2++) {
      const int k16 = s2 * 4 + quad;          // 16B granule 0..7
      longx2 a[4], b[4];
#pragma unroll
      for (int i = 0; i < 4; i++) {
        int r = wr * 64 + i * 16 + fm;
        a[i] = *(const longx2*)(sA + r * 128 + ((k16 ^ (r & 7)) * 16));
      }
#pragma unroll
      for (int j = 0; j < 4; j++) {
        int r = wc * 64 + j * 16 + fm;
        b[j] = *(const longx2*)(sB + r * 128 + ((k16 ^ (r & 7)) * 16));
      }
#pragma unroll
      for (int i = 0; i < 4; i++)
#pragma unroll
        for (int j = 0; j < 4; j++) {
          acc[i][j] = __builtin_amdgcn_mfma_f32_16x16x32_fp8_fp8(a[i][0], b[j][0], acc[i][j], 0, 0, 0);
          acc[i][j] = __builtin_amdgcn_mfma_f32_16x16x32_fp8_fp8(a[i][1], b[j][1], acc[i][j], 0, 0, 0);
        }
    }
  }

  // ---- epilogue ----
  float bj4[4];
#pragma unroll
  for (int j = 0; j < 4; j++) bj4[j] = bias[n0 + wc * 64 + j * 16 + fm];

  __syncthreads();                        // staging LDS dead
  float* ls = (float*)lds;                // 128 cols x 2 stats (1 KB)
  if (tid < 256) ls[tid] = 0.f;
  __syncthreads();
#pragma unroll
  for (int j = 0; j < 4; j++) {
    int colloc = wc * 64 + j * 16 + fm;
    float sj = 0.f, qj = 0.f;
#pragma unroll
    for (int i = 0; i < 4; i++)
#pragma unroll
      for (int r = 0; r < 4; r++) {
        float f = acc[i][j][r] + bj4[j];
        sj += f; qj = fmaf(f, f, qj);
      }
    atomicAdd(&ls[colloc * 2], sj);
    atomicAdd(&ls[colloc * 2 + 1], qj);
  }
  __syncthreads();
  if (tid < 128) {
    float* p = pstat + (size_t)mb * 1024 + (size_t)(n0 + tid) * 2;
    p[0] = ls[tid * 2];
    p[1] = ls[tid * 2 + 1];
  }
  __syncthreads();

  // bounce acc -> sC bf16 (stride 132: rows shift 2 banks), fp8-pack, 16B row stores
  uint16_t* sC = (uint16_t*)lds;          // 128 x 132 u16 = 33792 B
#pragma unroll
  for (int j = 0; j < 4; j++) {
    int col = wc * 64 + j * 16 + fm;
#pragma unroll
    for (int i = 0; i < 4; i++) {
      int rb = wr * 64 + i * 16 + quad * 4;
#pragma unroll
      for (int r = 0; r < 4; r++)
        sC[(rb + r) * 132 + col] = (uint16_t)f2bf_u(acc[i][j][r] + bj4[j]);
    }
  }
  __syncthreads();
#pragma unroll
  for (int r2 = 0; r2 < 4; r2++) {
    int row = r2 * 32 + (tid >> 3);
    int oc16 = (tid & 7) * 16;            // 16 cols per 16B store
    uint4 va = *(const uint4*)(sC + row * 132 + oc16);
    uint4 vb = *(const uint4*)(sC + row * 132 + oc16 + 8);
    uint32_t wv[8] = {va.x, va.y, va.z, va.w, vb.x, vb.y, vb.z, vb.w};
    uint4 o8;
    uint32_t* op = (uint32_t*)&o8;
#pragma unroll
    for (int q = 0; q < 4; q++) {
      uint32_t p8 = __builtin_amdgcn_cvt_pk_fp8_f32(bflo(wv[2 * q]), bfhi(wv[2 * q]), 0u, false);
      p8 = __builtin_amdgcn_cvt_pk_fp8_f32(bflo(wv[2 * q + 1]), bfhi(wv[2 * q + 1]), p8, true);
      op[q] = p8;
    }
    *(uint4*)(Z2 + (size_t)(m0 + row) * HH + n0 + oc16) = o8;
  }
}

// ---------- BN+ReLU + per-graph-id readout sums (fp8 z2 in; h2 never materialized) ----------
__global__ void bn2_readout(const uint32_t* __restrict__ z2, const float* __restrict__ scsh,
                            const int* __restrict__ gids1, const int* __restrict__ gids2,
                            float* __restrict__ readout, float* __restrict__ cnt) {
  int blk = blockIdx.x;                // 512 blocks x 128 rows (within one 512-row subgraph)
  int r0 = blk * 128;
  int g = r0 >> 15;
  int lr = r0 & (NN - 1);
  int gid = (g ? gids2 : gids1)[lr];
  int t = threadIdx.x;                 // 256: cg = u32 col group (4 cols), rh = row half
  int cg = t & 127, rh = t >> 7;
  const float* ss = scsh + (size_t)g * HH * 2 + cg * 8;
  float4 s0 = *(const float4*)ss, s1 = *(const float4*)(ss + 4);
  f32x2 sc01 = f32x2{s0.x, s0.z}, sh01 = f32x2{s0.y, s0.w};
  f32x2 sc23 = f32x2{s1.x, s1.z}, sh23 = f32x2{s1.y, s1.w};
  const uint32_t* p = z2 + (size_t)(r0 + rh * 64) * 128 + cg;
  f32x2 a01 = f32x2{0.f, 0.f}, a23 = f32x2{0.f, 0.f};
  for (int r = 0; r < 64; r++) {
    uint32_t w = p[(size_t)r * 128];
    f32x2 f01 = __builtin_amdgcn_cvt_pk_f32_fp8(w, false);
    f32x2 f23 = __builtin_amdgcn_cvt_pk_f32_fp8(w, true);
    f32x2 y0 = f01 * sc01 + sh01;
    f32x2 y1 = f23 * sc23 + sh23;
    y0.x = fmaxf(y0.x, 0.f); y0.y = fmaxf(y0.y, 0.f);
    y1.x = fmaxf(y1.x, 0.f); y1.y = fmaxf(y1.y, 0.f);
    a01 += y0; a23 += y1;
  }
  __shared__ float sr2[128][4];
  if (rh) { sr2[cg][0] = a01.x; sr2[cg][1] = a01.y; sr2[cg][2] = a23.x; sr2[cg][3] = a23.y; }
  __syncthreads();
  if (!rh) {
    float* ro = readout + ((size_t)g * BB + gid) * HH;
    atomicAdd(&ro[cg * 4 + 0], a01.x + sr2[cg][0]);
    atomicAdd(&ro[cg * 4 + 1], a01.y + sr2[cg][1]);
    atomicAdd(&ro[cg * 4 + 2], a23.x + sr2[cg][2]);
    atomicAdd(&ro[cg * 4 + 3], a23.y + sr2[cg][3]);
  }
  if (t == 0) atomicAdd(&cnt[g * BB + gid], 128.f);
}

// ---------- head: concat -> fc relu -> fc2 sigmoid ----------
__global__ void final_kernel(const float* __restrict__ readout, const float* __restrict__ cnt,
                             const float* __restrict__ Wfc, const float* __restrict__ bfc,
                             const float* __restrict__ Wfc2, const float* __restrict__ bfc2,
                             float* __restrict__ out) {
  __shared__ float x[1024];
  __shared__ float red[256];
  int b = blockIdx.x, t = threadIdx.x;
  for (int i = t; i < 1024; i += 256) {
    int g = i >> 9, c = i & 511;
    float cc = cnt[g * BB + b];
    x[i] = readout[((size_t)g * BB + b) * HH + c] / fmaxf(cc, 1.f);
  }
  __syncthreads();
  float a0 = 0.f, a1 = 0.f, a2 = 0.f, a3 = 0.f;   // 4-way ILP: break the dep chain
  for (int i = 0; i < 1024; i += 4) {
    a0 = fmaf(x[i],     Wfc[(size_t)i * 256 + t],       a0);
    a1 = fmaf(x[i + 1], Wfc[(size_t)(i + 1) * 256 + t], a1);
    a2 = fmaf(x[i + 2], Wfc[(size_t)(i + 2) * 256 + t], a2);
    a3 = fmaf(x[i + 3], Wfc[(size_t)(i + 3) * 256 + t], a3);
  }
  float acc = bfc[t] + ((a0 + a1) + (a2 + a3));
  red[t] = fmaxf(acc, 0.f) * Wfc2[t];
  __syncthreads();
  for (int s = 128; s > 0; s >>= 1) {
    if (t < s) red[t] += red[t + s];
    __syncthreads();
  }
  if (t == 0) out[b] = 1.f / (1.f + expf(-(red[0] + bfc2[0])));
}

// ---------- launch ----------
extern "C" void kernel_launch(void* const* d_in, const int* in_sizes, int n_in,
                              void* d_out, int out_size, void* d_ws, size_t ws_size,
                              hipStream_t stream) {
  const float* x1 = (const float*)d_in[0];
  const float* x2 = (const float*)d_in[1];
  const int* src1 = (const int*)d_in[2];
  const int* dst1 = (const int*)d_in[3];
  const int* src2 = (const int*)d_in[4];
  const int* dst2 = (const int*)d_in[5];
  const int* gids1 = (const int*)d_in[6];
  const int* gids2 = (const int*)d_in[7];
  const float* Wi = (const float*)d_in[8];
  const float* bi = (const float*)d_in[9];
  const float* W1 = (const float*)d_in[10];
  const float* b1 = (const float*)d_in[11];
  const float* W2 = (const float*)d_in[12];
  const float* b2 = (const float*)d_in[13];
  const float* gamma1 = (const float*)d_in[14];
  const float* beta1 = (const float*)d_in[15];
  const float* gamma2 = (const float*)d_in[16];
  const float* beta2 = (const float*)d_in[17];
  const float* Wfc = (const float*)d_in[18];
  const float* bfc = (const float*)d_in[19];
  const float* Wfc2 = (const float*)d_in[20];
  const float* bfc2 = (const float*)d_in[21];
  float* out = (float*)d_out;

  // workspace layout (256B-aligned slabs)
  size_t off = 0;
  auto alloc = [&](size_t bytes) -> void* {
    void* p = (char*)d_ws + off;
    off += (bytes + 255) & ~(size_t)255;
    return p;
  };
  uint32_t* z8 = (uint32_t*)alloc((size_t)MM * HH);          // fp8 z1 (32 MB)
  uint32_t* u8 = (uint32_t*)alloc((size_t)MM * HH);          // fp8 u2 (GEMM A operand)
  uint8_t* z2o = (uint8_t*)alloc((size_t)MM * HH);           // fp8 z2 (GEMM out, 32 MB)
  uint32_t* Wt8 = (uint32_t*)alloc((size_t)HH * HH);         // fp8 W2^T (256 KB)
  float* Wf = (float*)alloc((size_t)(DIN + 1) * HH * 4);
  int* csr = (int*)alloc((size_t)2 * EE * 4);
  int* offsets = (int*)alloc((size_t)2 * (NN + 1) * 4);
  int* cursor = (int*)alloc((size_t)2 * NN * 4);
  float* pbuf1 = (float*)alloc((size_t)512 * 512 * 2 * 4);   // z1 per-block col stats
  float* pbuf2 = (float*)alloc((size_t)512 * 512 * 2 * 4);   // gemm per-mtile col stats
  size_t zero_begin = off;
  int* deg_cnt = (int*)alloc((size_t)2 * NN * 4);
  float* readout = (float*)alloc((size_t)2 * BB * HH * 4);
  float* cnt = (float*)alloc((size_t)2 * BB * 4);
  size_t zero_end = off;
  float* scsh1 = (float*)alloc((size_t)2 * HH * 2 * 4);
  float* scsh2 = (float*)alloc((size_t)2 * HH * 2 * 4);
  (void)ws_size; (void)in_sizes; (void)n_in; (void)out_size;

  hipMemsetAsync((char*)d_ws + zero_begin, 0, zero_end - zero_begin, stream);

  // weights + CSR build (deg + W2->fp8 transpose + fold in one launch)
  prep_deg_kernel<<<2304 + 42, 256, 0, stream>>>(dst1, dst2, deg_cnt, W2, Wt8, Wi, bi, W1, Wf);
  scan_kernel<<<2, 1024, 0, stream>>>(deg_cnt, offsets, cursor);
  scatter_kernel<<<2048, 256, 0, stream>>>(src1, dst1, src2, dst2, cursor, csr);

  // layer 1 (GEMM folded, xagg fused): z1 -> z8 (fp8) + fused stats -> reduce -> scsh1
  z1_kernel<<<MM / 128, 512, 0, stream>>>(x1, x2, csr, offsets, Wf, b1, z8, pbuf1);
  reduce_stats<<<32, 256, 0, stream>>>(pbuf1, gamma1, beta1, scsh1, 256);

  // layer 2: aggbn(z8)->u8(fp8) ; fp8 gemm -> z2(fp8) (+fused stats) ; reduce ; bn2+readout
  aggbn_kernel<<<MM / 4, 256, 0, stream>>>(z8, u8, csr, offsets, scsh1);
  gemm_kernel<<<2048, 256, 0, stream>>>((const uint8_t*)u8, (const uint8_t*)Wt8, b2, z2o, pbuf2);
  reduce_stats<<<32, 256, 0, stream>>>(pbuf2, gamma2, beta2, scsh2, 256);
  bn2_readout<<<512, 256, 0, stream>>>((const uint32_t*)z2o, scsh2, gids1, gids2, readout, cnt);

  // head
  final_kernel<<<BB, 256, 0, stream>>>(readout, cnt, Wfc, bfc, Wfc2, bfc2, out);
}